// Round 2
// baseline (5969.033 us; speedup 1.0000x reference)
//
#include <hip/hip_runtime.h>

#define B_ 256
#define S_ 512
#define E_ 128
#define H_ 256
#define FH_ 1024
#define HROW 264  // 256 + 8 pad (shorts): row stride 132 dwords -> minimal bank cycles for b128

typedef __bf16 bf16x8 __attribute__((ext_vector_type(8)));
typedef float f32x4 __attribute__((ext_vector_type(4)));
typedef unsigned short u16x8 __attribute__((ext_vector_type(8)));

__device__ __forceinline__ unsigned short f2bf(float f) {
  union { float f; unsigned int u; } a; a.f = f;
  unsigned int u = a.u;
  u += 0x7fffu + ((u >> 16) & 1u);  // RNE
  return (unsigned short)(u >> 16);
}
__device__ __forceinline__ float bf2f(unsigned short v) {
  union { unsigned int u; float f; } a; a.u = ((unsigned int)v) << 16;
  return a.f;
}
__device__ __forceinline__ float sigm(float x) { return 1.f / (1.f + __expf(-x)); }
__device__ __forceinline__ float tanh_(float x) {
  float e = __expf(2.f * x);
  return 1.f - 2.f / (e + 1.f);
}

// ---------------- workspace layout (bytes) ----------------
#define OFF_ENC    ((size_t)0)          // enc_out bf16 [256][512][256]  67108864
#define OFF_WHHE   ((size_t)67108864)   // enc_Whh bf16 [1024][256]        524288
#define OFF_WHHP   ((size_t)67633152)   // pb_Whh  bf16                    524288
#define OFF_BLDSE  ((size_t)68157440)   // enc Whh kt6..7 frag-order bf16  131072
#define OFF_BLDSP  ((size_t)68288512)   // pb  Whh kt6..7 frag-order bf16  131072
#define OFF_WREF   ((size_t)68419584)   // Wref    bf16 [256][256]         131072
#define OFF_M3     ((size_t)68550656)   // (m0,m1,bias) f32 [1024][3]       12288
#define OFF_X3     ((size_t)68562944)   // (0,0,xpv)   f32 [1024][3]        12288
#define OFF_HFIN   ((size_t)68575232)   // final h f32 [256][256]          262144
#define OFF_QBUF   ((size_t)68837376)   // q f32 [256][256]                262144
#define OFF_UBUF   ((size_t)69099520)   // u f32 [256][512]                524288

// LDS layout inside k1 (dynamic, 151936 B total):
//   Bs   @0       131072  (128 frags of 1KB: [f][lane][8 bf16], f=(nt*2+kt'), nt=0..63)
//   hbuf @131072    8448  (bf16 [16][HROW])
//   xb   @139520   12288  (f32 [1024][3]  = m0,m1,bias per gate col)
//   xin  @151808     128  (f32 [16][2])
#define LDS_BYTES 151936

// ---------------- K0: prep ----------------
__global__ void k0_prep(const float* __restrict__ eWih, const float* __restrict__ eWhh,
                        const float* __restrict__ ebih, const float* __restrict__ ebhh,
                        const float* __restrict__ pWih, const float* __restrict__ pWhh,
                        const float* __restrict__ pbih, const float* __restrict__ pbhh,
                        const float* __restrict__ W_emb, const float* __restrict__ dec_in,
                        const float* __restrict__ Wref,
                        unsigned short* __restrict__ WhhE, unsigned short* __restrict__ WhhP,
                        unsigned short* __restrict__ BldsE, unsigned short* __restrict__ BldsP,
                        unsigned short* __restrict__ Wrefb,
                        float* __restrict__ M3, float* __restrict__ X3,
                        float* __restrict__ ubuf) {
  int gid = blockIdx.x * blockDim.x + threadIdx.x;
  int NT = gridDim.x * blockDim.x;
  for (int i = gid; i < FH_ * H_; i += NT) {
    WhhE[i] = f2bf(eWhh[i]);
    WhhP[i] = f2bf(pWhh[i]);
  }
  // frag-ordered copies of kt-tiles 6,7 (K in [192,256))
  for (int i = gid; i < 65536; i += NT) {
    int f = i >> 9, lane = (i >> 3) & 63, j = i & 7;
    int nt = f >> 1, ktp = f & 1, l16 = lane & 15, q = lane >> 4;
    int src = (nt * 16 + l16) * H_ + 192 + ktp * 32 + q * 8 + j;
    BldsE[i] = f2bf(eWhh[src]);
    BldsP[i] = f2bf(pWhh[src]);
  }
  for (int i = gid; i < H_ * H_; i += NT) Wrefb[i] = f2bf(Wref[i]);
  for (int i = gid; i < B_ * S_; i += NT) ubuf[i] = 0.f;
  if (gid < FH_) {
    int n = gid;
    float m0 = 0.f, m1 = 0.f, xs = 0.f;
    for (int e = 0; e < E_; ++e) {
      float w = eWih[n * E_ + e];
      m0 += w * W_emb[e * 2 + 0];
      m1 += w * W_emb[e * 2 + 1];
      xs += pWih[n * E_ + e] * dec_in[e];
    }
    M3[n * 3 + 0] = m0;
    M3[n * 3 + 1] = m1;
    M3[n * 3 + 2] = ebih[n] + ebhh[n];
    X3[n * 3 + 0] = 0.f;
    X3[n * 3 + 1] = 0.f;
    X3[n * 3 + 2] = xs + pbih[n] + pbhh[n];
  }
}

// ---------------- K1: single-WG-per-group resident LSTM ----------------
// 16 WGs x 512 threads; WG g owns batch rows [16g,16g+16) and ALL 1024 gate
// columns -> zero inter-WG communication. Whh: kt0..5 resident in VGPRs
// (48 frags = 192 regs/wave), kt6..7 in LDS (128 KB, frag-ordered).
__launch_bounds__(512, 2)
__global__ void k1_lstm(const float* __restrict__ inp,
                        const unsigned short* __restrict__ WhhE,
                        const unsigned short* __restrict__ WhhP,
                        const unsigned short* __restrict__ BldsE,
                        const unsigned short* __restrict__ BldsP,
                        const float* __restrict__ M3, const float* __restrict__ X3,
                        unsigned short* __restrict__ enc_out,
                        float* __restrict__ hfin) {
  extern __shared__ char smem[];
  unsigned short* Bs   = (unsigned short*)smem;             // 131072 B
  unsigned short* hbuf = (unsigned short*)(smem + 131072);  // 8448 B
  float* xb  = (float*)(smem + 139520);                     // 12288 B
  float* xin = (float*)(smem + 151808);                     // 128 B

  const int tid = threadIdx.x;
  const int wave = tid >> 6, lane = tid & 63, quad = lane >> 4, l16 = lane & 15;
  const int grp = blockIdx.x;  // 0..15
  const int colbase = wave * 32 + l16;  // +p*16 for pass p

  for (int i = tid; i < 16 * HROW; i += 512) hbuf[i] = 0;

  float c[8] = {0.f, 0.f, 0.f, 0.f, 0.f, 0.f, 0.f, 0.f};
  float hregf[8] = {0.f, 0.f, 0.f, 0.f, 0.f, 0.f, 0.f, 0.f};
  unsigned short hb8[8] = {0, 0, 0, 0, 0, 0, 0, 0};
  bf16x8 Bf[4][2][6];
  const f32x4 z4 = {0.f, 0.f, 0.f, 0.f};

  for (int phase = 0; phase < 2; ++phase) {
    const unsigned short* W  = phase ? WhhP : WhhE;
    const unsigned short* BL = phase ? BldsP : BldsE;
    const float* X = phase ? X3 : M3;
    // stage LDS weight tiles (kt6,7): 8192 16B-chunks
    for (int i = tid; i < 8192; i += 512)
      *(u16x8*)(Bs + i * 8) = *(const u16x8*)(BL + i * 8);
    // stage xb
    for (int i = tid; i < 3072; i += 512) xb[i] = X[i];
    // resident weight frags kt0..5
#pragma unroll
    for (int gg = 0; gg < 4; ++gg)
#pragma unroll
      for (int p = 0; p < 2; ++p) {
        int n = gg * 256 + colbase + p * 16;
#pragma unroll
        for (int kt = 0; kt < 6; ++kt)
          Bf[gg][p][kt] = *(const bf16x8*)(W + n * H_ + kt * 32 + quad * 8);
      }
    if (tid < 32) {
      xin[tid] = phase ? 0.f
                       : inp[((grp * 16 + (tid >> 1)) * S_ + 0) * 2 + (tid & 1)];
    }
    __syncthreads();

    for (int step = 0; step < 512; ++step) {
      // delayed enc_out store: h(step-1), in flight during this step's MFMA
      if (phase == 0 && step > 0) {
#pragma unroll
        for (int i = 0; i < 8; ++i) {
          int p = i >> 2, r = i & 3;
          enc_out[(((size_t)(grp * 16 + quad * 4 + r)) * S_ + (step - 1)) * H_ +
                  colbase + p * 16] = hb8[i];
        }
      }
      // x values for this step's 4 rows (broadcast reads)
      float x0r[4], x1r[4];
#pragma unroll
      for (int r = 0; r < 4; ++r) {
        x0r[r] = xin[(quad * 4 + r) * 2 + 0];
        x1r[r] = xin[(quad * 4 + r) * 2 + 1];
      }
#pragma unroll
      for (int p = 0; p < 2; ++p) {
        f32x4 acc[4];
#pragma unroll
        for (int kt = 0; kt < 8; ++kt) {
          bf16x8 Af = *(const bf16x8*)(hbuf + l16 * HROW + kt * 32 + quad * 8);
#pragma unroll
          for (int gg = 0; gg < 4; ++gg) {
            bf16x8 Bfr;
            if (kt < 6) {
              Bfr = Bf[gg][p][kt];
            } else {
              int f = (gg * 16 + wave * 2 + p) * 2 + (kt - 6);
              Bfr = *(const bf16x8*)(Bs + f * 512 + lane * 8);
            }
            acc[gg] = __builtin_amdgcn_mfma_f32_16x16x32_bf16(
                Af, Bfr, (kt == 0) ? z4 : acc[gg], 0, 0, 0);
          }
        }
        // gates for this pass's 16 columns
        float m0g[4], m1g[4], bg[4];
#pragma unroll
        for (int gg = 0; gg < 4; ++gg) {
          int base = (gg * 256 + colbase + p * 16) * 3;
          m0g[gg] = xb[base + 0];
          m1g[gg] = xb[base + 1];
          bg[gg]  = xb[base + 2];
        }
#pragma unroll
        for (int r = 0; r < 4; ++r) {
          float x0 = x0r[r], x1 = x1r[r];
          float gi = acc[0][r] + x0 * m0g[0] + x1 * m1g[0] + bg[0];
          float gf = acc[1][r] + x0 * m0g[1] + x1 * m1g[1] + bg[1];
          float gc = acc[2][r] + x0 * m0g[2] + x1 * m1g[2] + bg[2];
          float go = acc[3][r] + x0 * m0g[3] + x1 * m1g[3] + bg[3];
          float cn = sigm(gf) * c[p * 4 + r] + sigm(gi) * tanh_(gc);
          c[p * 4 + r] = cn;
          float hv = sigm(go) * tanh_(cn);
          hb8[p * 4 + r] = f2bf(hv);
          if (phase == 1 && step == 511) hregf[p * 4 + r] = hv;
        }
      }
      __syncthreads();  // (1) all A-frag reads of h(step-1) complete
#pragma unroll
      for (int i = 0; i < 8; ++i) {
        int p = i >> 2, r = i & 3;
        hbuf[(quad * 4 + r) * HROW + colbase + p * 16] = hb8[i];
      }
      if (phase == 0 && tid < 32) {
        int s2 = (step + 1 < 512) ? step + 1 : 511;
        xin[tid] = inp[((grp * 16 + (tid >> 1)) * S_ + s2) * 2 + (tid & 1)];
      }
      __syncthreads();  // (2) h(step) visible for next step
    }
    if (phase == 0) {  // flush h(511)
#pragma unroll
      for (int i = 0; i < 8; ++i) {
        int p = i >> 2, r = i & 3;
        enc_out[(((size_t)(grp * 16 + quad * 4 + r)) * S_ + 511) * H_ +
                colbase + p * 16] = hb8[i];
      }
    }
    __syncthreads();  // protect LDS restage of next phase
  }
  // final h (fp32) for the attention query
#pragma unroll
  for (int i = 0; i < 8; ++i) {
    int p = i >> 2, r = i & 3;
    hfin[(grp * 16 + quad * 4 + r) * H_ + colbase + p * 16] = hregf[i];
  }
}

// ---------------- K1b: q = h @ Wq^T + bq (fp32) ----------------
__global__ void k1b_q(const float* __restrict__ hfin, const float* __restrict__ Wq,
                      const float* __restrict__ bq, float* __restrict__ qbuf) {
  __shared__ float hl[H_];
  int b = blockIdx.x, j = threadIdx.x;
  hl[j] = hfin[b * H_ + j];
  __syncthreads();
  float s = bq[j];
  const float* w = Wq + j * H_;
  for (int k = 0; k < H_; ++k) s += hl[k] * w[k];
  qbuf[b * H_ + j] = s;
}

// ---------------- K2: u = tanh(enc_out@Wref^T + bref + q) @ V (fused) ----------
__launch_bounds__(512)
__global__ void k2_att(const unsigned short* __restrict__ enc_out,
                       const unsigned short* __restrict__ Wrefb,
                       const float* __restrict__ qbuf, const float* __restrict__ bref,
                       const float* __restrict__ V, float* __restrict__ ubuf) {
  __shared__ unsigned short Bsh[128 * HROW];
  __shared__ float qs[128], Vs[128];
  int tid = threadIdx.x;
  int wave = tid >> 6, lane = tid & 63, quad = lane >> 4, l16 = lane & 15;
  int rowblk = blockIdx.x >> 1, nb = blockIdx.x & 1;
  int b = rowblk >> 2;
  {  // stage Wref block [nb*128 .. +128) x 256 into LDS
    int nl = tid >> 2, seg = tid & 3;
    const unsigned short* src = Wrefb + (nb * 128 + nl) * H_ + seg * 64;
    unsigned short* dst = Bsh + nl * HROW + seg * 64;
#pragma unroll
    for (int i = 0; i < 8; ++i) *(u16x8*)(dst + i * 8) = *(const u16x8*)(src + i * 8);
  }
  if (tid < 128) {
    int j = nb * 128 + tid;
    qs[tid] = qbuf[b * H_ + j] + bref[j];
    Vs[tid] = V[j];
  }
  __syncthreads();
  int rw = rowblk * 128 + wave * 16 + l16;  // global (b,s) row
  const f32x4 z4 = {0.f, 0.f, 0.f, 0.f};
  f32x4 acc[8];
#pragma unroll
  for (int kt = 0; kt < 8; ++kt) {
    bf16x8 af = *(const bf16x8*)(enc_out + (size_t)rw * H_ + kt * 32 + quad * 8);
#pragma unroll
    for (int nt = 0; nt < 8; ++nt) {
      bf16x8 bfr = *(const bf16x8*)(Bsh + (nt * 16 + l16) * HROW + kt * 32 + quad * 8);
      acc[nt] = __builtin_amdgcn_mfma_f32_16x16x32_bf16(af, bfr, (kt == 0) ? z4 : acc[nt],
                                                        0, 0, 0);
    }
  }
  float part[4] = {0.f, 0.f, 0.f, 0.f};
#pragma unroll
  for (int nt = 0; nt < 8; ++nt) {
    float qv = qs[nt * 16 + l16], vv = Vs[nt * 16 + l16];
#pragma unroll
    for (int r = 0; r < 4; ++r) part[r] += tanh_(acc[nt][r] + qv) * vv;
  }
#pragma unroll
  for (int m = 1; m < 16; m <<= 1) {
#pragma unroll
    for (int r = 0; r < 4; ++r) part[r] += __shfl_xor(part[r], m, 64);
  }
  if (l16 == 0) {
    int s0 = (rowblk & 3) * 128 + wave * 16 + quad * 4;
#pragma unroll
    for (int r = 0; r < 4; ++r) atomicAdd(&ubuf[b * S_ + s0 + r], part[r]);
  }
}

// ---------------- K3: softmax + glimpse + decoder head ----------------
__global__ void k3_head(const float* __restrict__ ubuf,
                        const unsigned short* __restrict__ enc_out,
                        const float* __restrict__ Wd1, const float* __restrict__ Wd2,
                        float* __restrict__ out) {
  __shared__ float sm[512];
  __shared__ float red[256];
  __shared__ float gl[256];
  int b = blockIdx.x, tid = threadIdx.x;
  float u0 = ubuf[b * S_ + tid], u1 = ubuf[b * S_ + 256 + tid];
  red[tid] = fmaxf(u0, u1);
  __syncthreads();
  for (int s = 128; s > 0; s >>= 1) {
    if (tid < s) red[tid] = fmaxf(red[tid], red[tid + s]);
    __syncthreads();
  }
  float mx = red[0];
  __syncthreads();
  float e0 = __expf(u0 - mx), e1 = __expf(u1 - mx);
  red[tid] = e0 + e1;
  __syncthreads();
  for (int s = 128; s > 0; s >>= 1) {
    if (tid < s) red[tid] += red[tid + s];
    __syncthreads();
  }
  float inv = 1.f / red[0];
  sm[tid] = e0 * inv;
  sm[256 + tid] = e1 * inv;
  __syncthreads();
  float g = 0.f;
  const unsigned short* eo = enc_out + (size_t)b * S_ * H_ + tid;
  for (int s = 0; s < S_; ++s) g += sm[s] * bf2f(eo[(size_t)s * H_]);
  gl[tid] = g;
  __syncthreads();
  float y = 0.f;
  const float* w = Wd1 + tid * H_;
  for (int j = 0; j < H_; ++j) y += w[j] * gl[j];
  y = fmaxf(y, 0.f) * Wd2[tid];
  red[tid] = y;
  __syncthreads();
  for (int s = 128; s > 0; s >>= 1) {
    if (tid < s) red[tid] += red[tid + s];
    __syncthreads();
  }
  if (tid == 0) out[b] = red[0];
}

extern "C" void kernel_launch(void* const* d_in, const int* in_sizes, int n_in,
                              void* d_out, int out_size, void* d_ws, size_t ws_size,
                              hipStream_t stream) {
  (void)in_sizes; (void)n_in; (void)out_size; (void)ws_size;
  const float* inp    = (const float*)d_in[0];
  const float* W_emb  = (const float*)d_in[1];
  const float* dec_in = (const float*)d_in[2];
  const float* eWih   = (const float*)d_in[3];
  const float* eWhh   = (const float*)d_in[4];
  const float* ebih   = (const float*)d_in[5];
  const float* ebhh   = (const float*)d_in[6];
  const float* pWih   = (const float*)d_in[7];
  const float* pWhh   = (const float*)d_in[8];
  const float* pbih   = (const float*)d_in[9];
  const float* pbhh   = (const float*)d_in[10];
  const float* Wq     = (const float*)d_in[11];
  const float* bq     = (const float*)d_in[12];
  const float* Wref   = (const float*)d_in[13];
  const float* bref   = (const float*)d_in[14];
  const float* V      = (const float*)d_in[15];
  const float* Wd1    = (const float*)d_in[16];
  const float* Wd2    = (const float*)d_in[17];
  float* out = (float*)d_out;

  char* ws = (char*)d_ws;
  unsigned short* enc_out = (unsigned short*)(ws + OFF_ENC);
  unsigned short* WhhE    = (unsigned short*)(ws + OFF_WHHE);
  unsigned short* WhhP    = (unsigned short*)(ws + OFF_WHHP);
  unsigned short* BldsE   = (unsigned short*)(ws + OFF_BLDSE);
  unsigned short* BldsP   = (unsigned short*)(ws + OFF_BLDSP);
  unsigned short* Wrefb   = (unsigned short*)(ws + OFF_WREF);
  float* M3   = (float*)(ws + OFF_M3);
  float* X3   = (float*)(ws + OFF_X3);
  float* hfin = (float*)(ws + OFF_HFIN);
  float* qbuf = (float*)(ws + OFF_QBUF);
  float* ubuf = (float*)(ws + OFF_UBUF);

  // opt-in to >64KB dynamic LDS (idempotent; not a stream op, capture-safe)
  hipFuncSetAttribute((const void*)k1_lstm,
                      hipFuncAttributeMaxDynamicSharedMemorySize, LDS_BYTES);

  hipLaunchKernelGGL(k0_prep, dim3(256), dim3(256), 0, stream,
                     eWih, eWhh, ebih, ebhh, pWih, pWhh, pbih, pbhh, W_emb, dec_in,
                     Wref, WhhE, WhhP, BldsE, BldsP, Wrefb, M3, X3, ubuf);
  hipLaunchKernelGGL(k1_lstm, dim3(16), dim3(512), LDS_BYTES, stream,
                     inp, WhhE, WhhP, BldsE, BldsP, M3, X3, enc_out, hfin);
  hipLaunchKernelGGL(k1b_q, dim3(256), dim3(256), 0, stream, hfin, Wq, bq, qbuf);
  hipLaunchKernelGGL(k2_att, dim3(2048), dim3(512), 0, stream,
                     enc_out, Wrefb, qbuf, bref, V, ubuf);
  hipLaunchKernelGGL(k3_head, dim3(256), dim3(256), 0, stream,
                     ubuf, enc_out, Wd1, Wd2, out);
}

// Round 3
// 5328.472 us; speedup vs baseline: 1.1202x; 1.1202x over previous
//
#include <hip/hip_runtime.h>

#define B_ 256
#define S_ 512
#define E_ 128
#define H_ 256
#define FH_ 1024
#define HROW 264  // 256 + 8 pad (shorts): row stride 132 dwords, 2-way max (free)

typedef __bf16 bf16x8 __attribute__((ext_vector_type(8)));
typedef float f32x4 __attribute__((ext_vector_type(4)));
typedef unsigned short u16x8 __attribute__((ext_vector_type(8)));

__device__ __forceinline__ unsigned short f2bf(float f) {
  union { float f; unsigned int u; } a; a.f = f;
  unsigned int u = a.u;
  u += 0x7fffu + ((u >> 16) & 1u);  // RNE
  return (unsigned short)(u >> 16);
}
__device__ __forceinline__ float bf2f(unsigned short v) {
  union { unsigned int u; float f; } a; a.u = ((unsigned int)v) << 16;
  return a.f;
}
__device__ __forceinline__ float sigm(float x) { return 1.f / (1.f + __expf(-x)); }
__device__ __forceinline__ float tanh_(float x) {
  float e = __expf(2.f * x);
  return 1.f - 2.f / (e + 1.f);
}
// LDS-only barrier: does NOT drain vmcnt (global stores stay in flight)
__device__ __forceinline__ void barrier_lds() {
  asm volatile("s_waitcnt lgkmcnt(0)\n\ts_barrier" ::: "memory");
}

// ---------------- workspace layout (bytes) ----------------
#define OFF_ENC    ((size_t)0)          // enc_out bf16 [256][512][256]  67108864
#define OFF_WHHE   ((size_t)67108864)   // enc_Whh bf16 [1024][256]        524288
#define OFF_WHHP   ((size_t)67633152)   // pb_Whh  bf16                    524288
#define OFF_BLDSE  ((size_t)68157440)   // enc Whh kt6..7 frag-order bf16  131072
#define OFF_BLDSP  ((size_t)68288512)   // pb  Whh kt6..7 frag-order bf16  131072
#define OFF_WREF   ((size_t)68419584)   // Wref    bf16 [256][256]         131072
#define OFF_M3     ((size_t)68550656)   // (m0,m1,bias) f32 [1024][3]       12288
#define OFF_X3     ((size_t)68562944)   // (0,0,xpv)   f32 [1024][3]        12288
#define OFF_HFIN   ((size_t)68575232)   // final h f32 [256][256]          262144
#define OFF_QBUF   ((size_t)68837376)   // q f32 [256][256]                262144
#define OFF_UBUF   ((size_t)69099520)   // u f32 [256][512]                524288

// k1 dynamic LDS layout:
//   Bs    @0       131072  (128 frags of 1KB: f=(nt*2+ktp), per-lane 16B)
//   hbuf0 @131072    8448  (bf16 [16][HROW])
//   hbuf1 @139520    8448
//   xb    @147968   12288  (f32 [1024][3] = m0,m1,bias per gate col)
//   xin   @160256     256  (f32 [2][16][2])
#define LDS_BYTES 160512

// ---------------- K0: prep ----------------
__global__ void k0_prep(const float* __restrict__ eWih, const float* __restrict__ eWhh,
                        const float* __restrict__ ebih, const float* __restrict__ ebhh,
                        const float* __restrict__ pWih, const float* __restrict__ pWhh,
                        const float* __restrict__ pbih, const float* __restrict__ pbhh,
                        const float* __restrict__ W_emb, const float* __restrict__ dec_in,
                        const float* __restrict__ Wref,
                        unsigned short* __restrict__ WhhE, unsigned short* __restrict__ WhhP,
                        unsigned short* __restrict__ BldsE, unsigned short* __restrict__ BldsP,
                        unsigned short* __restrict__ Wrefb,
                        float* __restrict__ M3, float* __restrict__ X3,
                        float* __restrict__ ubuf) {
  int gid = blockIdx.x * blockDim.x + threadIdx.x;
  int NT = gridDim.x * blockDim.x;
  for (int i = gid; i < FH_ * H_; i += NT) {
    WhhE[i] = f2bf(eWhh[i]);
    WhhP[i] = f2bf(pWhh[i]);
  }
  // frag-ordered copies of kt-tiles 6,7 (K in [192,256)) -- layout verified r2
  for (int i = gid; i < 65536; i += NT) {
    int f = i >> 9, lane = (i >> 3) & 63, j = i & 7;
    int nt = f >> 1, ktp = f & 1, l16 = lane & 15, q = lane >> 4;
    int src = (nt * 16 + l16) * H_ + 192 + ktp * 32 + q * 8 + j;
    BldsE[i] = f2bf(eWhh[src]);
    BldsP[i] = f2bf(pWhh[src]);
  }
  for (int i = gid; i < H_ * H_; i += NT) Wrefb[i] = f2bf(Wref[i]);
  for (int i = gid; i < B_ * S_; i += NT) ubuf[i] = 0.f;
  if (gid < FH_) {
    int n = gid;
    float m0 = 0.f, m1 = 0.f, xs = 0.f;
    for (int e = 0; e < E_; ++e) {
      float w = eWih[n * E_ + e];
      m0 += w * W_emb[e * 2 + 0];
      m1 += w * W_emb[e * 2 + 1];
      xs += pWih[n * E_ + e] * dec_in[e];
    }
    M3[n * 3 + 0] = m0;
    M3[n * 3 + 1] = m1;
    M3[n * 3 + 2] = ebih[n] + ebhh[n];
    X3[n * 3 + 0] = 0.f;
    X3[n * 3 + 1] = 0.f;
    X3[n * 3 + 2] = xs + pbih[n] + pbhh[n];
  }
}

// ---------------- K1: single-WG-per-group resident LSTM ----------------
// 16 WGs x 512 threads; WG g owns batch rows [16g,16g+16) and ALL 1024 gate
// columns -> zero inter-WG traffic. Whh kt0..5 resident in VGPRs (192 regs),
// kt6..7 in LDS. amdgpu_waves_per_eu(2) => 256-reg budget (r2 failed at 128).
__global__ __launch_bounds__(512)
__attribute__((amdgpu_waves_per_eu(2)))
void k1_lstm(const float* __restrict__ inp,
             const unsigned short* __restrict__ WhhE,
             const unsigned short* __restrict__ WhhP,
             const unsigned short* __restrict__ BldsE,
             const unsigned short* __restrict__ BldsP,
             const float* __restrict__ M3, const float* __restrict__ X3,
             unsigned short* __restrict__ enc_out,
             float* __restrict__ hfin) {
  extern __shared__ char smem[];
  unsigned short* Bs    = (unsigned short*)smem;             // 131072
  unsigned short* hbuf0 = (unsigned short*)(smem + 131072);  // 8448
  unsigned short* hbuf1 = (unsigned short*)(smem + 139520);  // 8448
  float* xb  = (float*)(smem + 147968);                      // 12288
  float* xin = (float*)(smem + 160256);                      // 256

  const int tid = threadIdx.x;
  const int wave = tid >> 6, lane = tid & 63, quad = lane >> 4, l16 = lane & 15;
  const int grp = blockIdx.x;  // 0..15
  const int colbase = wave * 32 + l16;  // +p*16 for pass p

  float c[8] = {0.f, 0.f, 0.f, 0.f, 0.f, 0.f, 0.f, 0.f};
  unsigned short hb8[8] = {0, 0, 0, 0, 0, 0, 0, 0};
  bf16x8 Bf[4][2][6];  // 192 VGPRs resident weights (kt0..5)
  const f32x4 z4 = {0.f, 0.f, 0.f, 0.f};

  for (int phase = 0; phase < 2; ++phase) {
    const unsigned short* W  = phase ? WhhP : WhhE;
    const unsigned short* BL = phase ? BldsP : BldsE;
    const float* X = phase ? X3 : M3;
    // stage LDS weight tiles (kt6,7)
    for (int i = tid; i < 8192; i += 512)
      *(u16x8*)(Bs + i * 8) = *(const u16x8*)(BL + i * 8);
    for (int i = tid; i < 3072; i += 512) xb[i] = X[i];
    if (phase == 0) {
      for (int i = tid; i < 16 * HROW; i += 512) { hbuf0[i] = 0; hbuf1[i] = 0; }
      if (tid < 32)
        xin[tid] = inp[((grp * 16 + (tid >> 1)) * S_ + 0) * 2 + (tid & 1)];
    }
    // resident weight frags kt0..5
#pragma unroll
    for (int gg = 0; gg < 4; ++gg)
#pragma unroll
      for (int p = 0; p < 2; ++p) {
        int n = gg * 256 + colbase + p * 16;
#pragma unroll
        for (int kt = 0; kt < 6; ++kt)
          Bf[gg][p][kt] = *(const bf16x8*)(W + n * H_ + kt * 32 + quad * 8);
      }
    __syncthreads();

    for (int step = 0; step < 512; ++step) {
      const int t = phase * 512 + step;
      const unsigned short* hrd = (t & 1) ? hbuf1 : hbuf0;
      unsigned short* hwr = (t & 1) ? hbuf0 : hbuf1;
      // prefetch next x (phase 0 only; latency hidden across the step body)
      float xnext = 0.f;
      if (phase == 0 && tid < 32) {
        int s2 = (step + 1 < 512) ? step + 1 : 511;
        xnext = inp[((grp * 16 + (tid >> 1)) * S_ + s2) * 2 + (tid & 1)];
      }
      // ---- GEMM: single K-pass, A-frag read once per kt ----
      f32x4 acc[8];
#pragma unroll
      for (int kt = 0; kt < 8; ++kt) {
        bf16x8 Af = *(const bf16x8*)(hrd + l16 * HROW + kt * 32 + quad * 8);
#pragma unroll
        for (int p = 0; p < 2; ++p)
#pragma unroll
          for (int gg = 0; gg < 4; ++gg) {
            bf16x8 Bfr;
            if (kt < 6) {
              Bfr = Bf[gg][p][kt];
            } else {
              int f = (gg * 16 + wave * 2 + p) * 2 + (kt - 6);
              Bfr = *(const bf16x8*)(Bs + f * 512 + lane * 8);
            }
            acc[p * 4 + gg] = __builtin_amdgcn_mfma_f32_16x16x32_bf16(
                Af, Bfr, (kt == 0) ? z4 : acc[p * 4 + gg], 0, 0, 0);
          }
      }
      // ---- gates ----
#pragma unroll
      for (int p = 0; p < 2; ++p) {
        float m0g[4], m1g[4], bg[4];
#pragma unroll
        for (int gg = 0; gg < 4; ++gg) {
          int base = (gg * 256 + colbase + p * 16) * 3;
          bg[gg] = xb[base + 2];
          if (phase == 0) { m0g[gg] = xb[base + 0]; m1g[gg] = xb[base + 1]; }
        }
#pragma unroll
        for (int r = 0; r < 4; ++r) {
          float gi = acc[p * 4 + 0][r] + bg[0];
          float gf = acc[p * 4 + 1][r] + bg[1];
          float gc = acc[p * 4 + 2][r] + bg[2];
          float go = acc[p * 4 + 3][r] + bg[3];
          if (phase == 0) {
            float x0 = xin[(t & 1) * 32 + (quad * 4 + r) * 2 + 0];
            float x1 = xin[(t & 1) * 32 + (quad * 4 + r) * 2 + 1];
            gi += x0 * m0g[0] + x1 * m1g[0];
            gf += x0 * m0g[1] + x1 * m1g[1];
            gc += x0 * m0g[2] + x1 * m1g[2];
            go += x0 * m0g[3] + x1 * m1g[3];
          }
          float cn = sigm(gf) * c[p * 4 + r] + sigm(gi) * tanh_(gc);
          c[p * 4 + r] = cn;
          float hv = sigm(go) * tanh_(cn);
          hb8[p * 4 + r] = f2bf(hv);
          if (phase == 1 && step == 511)
            hfin[(grp * 16 + quad * 4 + r) * H_ + colbase + p * 16] = hv;
        }
      }
      // enc_out store (async; raw barrier below does NOT drain vmcnt)
      if (phase == 0) {
#pragma unroll
        for (int i = 0; i < 8; ++i) {
          int p = i >> 2, r = i & 3;
          enc_out[((grp * 16 + quad * 4 + r) * S_ + step) * H_ + colbase + p * 16] =
              hb8[i];
        }
      }
      // write h_t into the other buffer; publish next x
#pragma unroll
      for (int i = 0; i < 8; ++i) {
        int p = i >> 2, r = i & 3;
        hwr[(quad * 4 + r) * HROW + colbase + p * 16] = hb8[i];
      }
      if (phase == 0 && tid < 32) xin[((t + 1) & 1) * 32 + tid] = xnext;
      barrier_lds();  // single barrier per step (double-buffered h)
    }
  }
}

// ---------------- K1b: q = h @ Wq^T + bq (fp32) ----------------
__global__ void k1b_q(const float* __restrict__ hfin, const float* __restrict__ Wq,
                      const float* __restrict__ bq, float* __restrict__ qbuf) {
  __shared__ float hl[H_];
  int b = blockIdx.x, j = threadIdx.x;
  hl[j] = hfin[b * H_ + j];
  __syncthreads();
  float s = bq[j];
  const float* w = Wq + j * H_;
  for (int k = 0; k < H_; ++k) s += hl[k] * w[k];
  qbuf[b * H_ + j] = s;
}

// ---------------- K2: u = tanh(enc_out@Wref^T + bref + q) @ V (fused) ----------
__launch_bounds__(512)
__global__ void k2_att(const unsigned short* __restrict__ enc_out,
                       const unsigned short* __restrict__ Wrefb,
                       const float* __restrict__ qbuf, const float* __restrict__ bref,
                       const float* __restrict__ V, float* __restrict__ ubuf) {
  __shared__ unsigned short Bsh[128 * HROW];
  __shared__ float qs[128], Vs[128];
  int tid = threadIdx.x;
  int wave = tid >> 6, lane = tid & 63, quad = lane >> 4, l16 = lane & 15;
  int rowblk = blockIdx.x >> 1, nb = blockIdx.x & 1;
  int b = rowblk >> 2;
  {
    int nl = tid >> 2, seg = tid & 3;
    const unsigned short* src = Wrefb + (nb * 128 + nl) * H_ + seg * 64;
    unsigned short* dst = Bsh + nl * HROW + seg * 64;
#pragma unroll
    for (int i = 0; i < 8; ++i) *(u16x8*)(dst + i * 8) = *(const u16x8*)(src + i * 8);
  }
  if (tid < 128) {
    int j = nb * 128 + tid;
    qs[tid] = qbuf[b * H_ + j] + bref[j];
    Vs[tid] = V[j];
  }
  __syncthreads();
  int rw = rowblk * 128 + wave * 16 + l16;
  const f32x4 z4 = {0.f, 0.f, 0.f, 0.f};
  f32x4 acc[8];
#pragma unroll
  for (int kt = 0; kt < 8; ++kt) {
    bf16x8 af = *(const bf16x8*)(enc_out + (size_t)rw * H_ + kt * 32 + quad * 8);
#pragma unroll
    for (int nt = 0; nt < 8; ++nt) {
      bf16x8 bfr = *(const bf16x8*)(Bsh + (nt * 16 + l16) * HROW + kt * 32 + quad * 8);
      acc[nt] = __builtin_amdgcn_mfma_f32_16x16x32_bf16(af, bfr, (kt == 0) ? z4 : acc[nt],
                                                        0, 0, 0);
    }
  }
  float part[4] = {0.f, 0.f, 0.f, 0.f};
#pragma unroll
  for (int nt = 0; nt < 8; ++nt) {
    float qv = qs[nt * 16 + l16], vv = Vs[nt * 16 + l16];
#pragma unroll
    for (int r = 0; r < 4; ++r) part[r] += tanh_(acc[nt][r] + qv) * vv;
  }
#pragma unroll
  for (int m = 1; m < 16; m <<= 1) {
#pragma unroll
    for (int r = 0; r < 4; ++r) part[r] += __shfl_xor(part[r], m, 64);
  }
  if (l16 == 0) {
    int s0 = (rowblk & 3) * 128 + wave * 16 + quad * 4;
#pragma unroll
    for (int r = 0; r < 4; ++r) atomicAdd(&ubuf[b * S_ + s0 + r], part[r]);
  }
}

// ---------------- K3: softmax + glimpse + decoder head ----------------
__global__ void k3_head(const float* __restrict__ ubuf,
                        const unsigned short* __restrict__ enc_out,
                        const float* __restrict__ Wd1, const float* __restrict__ Wd2,
                        float* __restrict__ out) {
  __shared__ float sm[512];
  __shared__ float red[256];
  __shared__ float gl[256];
  int b = blockIdx.x, tid = threadIdx.x;
  float u0 = ubuf[b * S_ + tid], u1 = ubuf[b * S_ + 256 + tid];
  red[tid] = fmaxf(u0, u1);
  __syncthreads();
  for (int s = 128; s > 0; s >>= 1) {
    if (tid < s) red[tid] = fmaxf(red[tid], red[tid + s]);
    __syncthreads();
  }
  float mx = red[0];
  __syncthreads();
  float e0 = __expf(u0 - mx), e1 = __expf(u1 - mx);
  red[tid] = e0 + e1;
  __syncthreads();
  for (int s = 128; s > 0; s >>= 1) {
    if (tid < s) red[tid] += red[tid + s];
    __syncthreads();
  }
  float inv = 1.f / red[0];
  sm[tid] = e0 * inv;
  sm[256 + tid] = e1 * inv;
  __syncthreads();
  float g = 0.f;
  const unsigned short* eo = enc_out + (size_t)b * S_ * H_ + tid;
  for (int s = 0; s < S_; ++s) g += sm[s] * bf2f(eo[(size_t)s * H_]);
  gl[tid] = g;
  __syncthreads();
  float y = 0.f;
  const float* w = Wd1 + tid * H_;
  for (int j = 0; j < H_; ++j) y += w[j] * gl[j];
  y = fmaxf(y, 0.f) * Wd2[tid];
  red[tid] = y;
  __syncthreads();
  for (int s = 128; s > 0; s >>= 1) {
    if (tid < s) red[tid] += red[tid + s];
    __syncthreads();
  }
  if (tid == 0) out[b] = red[0];
}

extern "C" void kernel_launch(void* const* d_in, const int* in_sizes, int n_in,
                              void* d_out, int out_size, void* d_ws, size_t ws_size,
                              hipStream_t stream) {
  (void)in_sizes; (void)n_in; (void)out_size; (void)ws_size;
  const float* inp    = (const float*)d_in[0];
  const float* W_emb  = (const float*)d_in[1];
  const float* dec_in = (const float*)d_in[2];
  const float* eWih   = (const float*)d_in[3];
  const float* eWhh   = (const float*)d_in[4];
  const float* ebih   = (const float*)d_in[5];
  const float* ebhh   = (const float*)d_in[6];
  const float* pWih   = (const float*)d_in[7];
  const float* pWhh   = (const float*)d_in[8];
  const float* pbih   = (const float*)d_in[9];
  const float* pbhh   = (const float*)d_in[10];
  const float* Wq     = (const float*)d_in[11];
  const float* bq     = (const float*)d_in[12];
  const float* Wref   = (const float*)d_in[13];
  const float* bref   = (const float*)d_in[14];
  const float* V      = (const float*)d_in[15];
  const float* Wd1    = (const float*)d_in[16];
  const float* Wd2    = (const float*)d_in[17];
  float* out = (float*)d_out;

  char* ws = (char*)d_ws;
  unsigned short* enc_out = (unsigned short*)(ws + OFF_ENC);
  unsigned short* WhhE    = (unsigned short*)(ws + OFF_WHHE);
  unsigned short* WhhP    = (unsigned short*)(ws + OFF_WHHP);
  unsigned short* BldsE   = (unsigned short*)(ws + OFF_BLDSE);
  unsigned short* BldsP   = (unsigned short*)(ws + OFF_BLDSP);
  unsigned short* Wrefb   = (unsigned short*)(ws + OFF_WREF);
  float* M3   = (float*)(ws + OFF_M3);
  float* X3   = (float*)(ws + OFF_X3);
  float* hfin = (float*)(ws + OFF_HFIN);
  float* qbuf = (float*)(ws + OFF_QBUF);
  float* ubuf = (float*)(ws + OFF_UBUF);

  hipFuncSetAttribute((const void*)k1_lstm,
                      hipFuncAttributeMaxDynamicSharedMemorySize, LDS_BYTES);

  hipLaunchKernelGGL(k0_prep, dim3(256), dim3(256), 0, stream,
                     eWih, eWhh, ebih, ebhh, pWih, pWhh, pbih, pbhh, W_emb, dec_in,
                     Wref, WhhE, WhhP, BldsE, BldsP, Wrefb, M3, X3, ubuf);
  hipLaunchKernelGGL(k1_lstm, dim3(16), dim3(512), LDS_BYTES, stream,
                     inp, WhhE, WhhP, BldsE, BldsP, M3, X3, enc_out, hfin);
  hipLaunchKernelGGL(k1b_q, dim3(256), dim3(256), 0, stream, hfin, Wq, bq, qbuf);
  hipLaunchKernelGGL(k2_att, dim3(2048), dim3(512), 0, stream,
                     enc_out, Wrefb, qbuf, bref, V, ubuf);
  hipLaunchKernelGGL(k3_head, dim3(256), dim3(256), 0, stream,
                     ubuf, enc_out, Wd1, Wd2, out);
}